// Round 7
// baseline (337.611 us; speedup 1.0000x reference)
//
#include <hip/hip_runtime.h>
#include <math.h>

#define NB 8
#define NC 256
#define NHW 2304
#define NG 32
#define CPG 8
#define GN_EPS 1e-5f
#define ATT_SCALE 0.0625f
#define XSTR 258   // k_xnT transpose LDS stride (bf16)
#define PTSTR 68   // k_sexp f32 epilogue tile stride

typedef __bf16 bf16x8 __attribute__((ext_vector_type(8)));
typedef __bf16 bf16x4 __attribute__((ext_vector_type(4)));
typedef float f32x4 __attribute__((ext_vector_type(4)));

#define MFMA(a, b, c) __builtin_amdgcn_mfma_f32_16x16x32_bf16(a, b, c, 0, 0, 0)

__device__ __forceinline__ void async_lds16(const void* g, void* l) {
  __builtin_amdgcn_global_load_lds(
      (const __attribute__((address_space(1))) void*)g,
      (__attribute__((address_space(3))) void*)l, 16, 0, 0);
}

// ---------------------------------------------------------------------------
// Kernel 1: merged GN-stats (blocks 0..255) + W fp32->bf16 cast (256..447).
// ---------------------------------------------------------------------------
__global__ __launch_bounds__(256) void k_prep(
    const float* __restrict__ x, const float* __restrict__ gn_w,
    const float* __restrict__ gn_b, float* __restrict__ scale,
    float* __restrict__ shift,
    const float* __restrict__ Wq, const float* __restrict__ Wk,
    const float* __restrict__ Wv, __bf16* __restrict__ Wqb,
    __bf16* __restrict__ Wkb, __bf16* __restrict__ Wvb) {
  __shared__ float red[8];
  int blk = blockIdx.x;
  if (blk >= 256) {  // ---- weight cast ----
    int idx = blk - 256;
    int which = idx >> 6;
    const float* src = which == 0 ? Wq : (which == 1 ? Wk : Wv);
    __bf16* dst = which == 0 ? Wqb : (which == 1 ? Wkb : Wvb);
    int i = (idx & 63) * 256 + threadIdx.x;
    float4 v = ((const float4*)src)[i];
    bf16x4 o;
    o[0] = (__bf16)v.x; o[1] = (__bf16)v.y;
    o[2] = (__bf16)v.z; o[3] = (__bf16)v.w;
    ((bf16x4*)dst)[i] = o;
    return;
  }
  // ---- GroupNorm stats ----
  const float4* base = (const float4*)(x + (size_t)blk * CPG * NHW);
  const int n4 = CPG * NHW / 4;
  float s = 0.f, ss = 0.f;
  for (int i = threadIdx.x; i < n4; i += 256) {
    float4 v = base[i];
    s  += v.x + v.y + v.z + v.w;
    ss += v.x * v.x + v.y * v.y + v.z * v.z + v.w * v.w;
  }
  for (int off = 32; off > 0; off >>= 1) {
    s  += __shfl_down(s, off);
    ss += __shfl_down(ss, off);
  }
  int wv = threadIdx.x >> 6, ln = threadIdx.x & 63;
  if (ln == 0) { red[wv] = s; red[4 + wv] = ss; }
  __syncthreads();
  if (threadIdx.x < CPG) {
    float S  = red[0] + red[1] + red[2] + red[3];
    float SS = red[4] + red[5] + red[6] + red[7];
    const float inv_n = 1.f / (float)(CPG * NHW);
    float mean = S * inv_n;
    float var  = SS * inv_n - mean * mean;
    float rstd = rsqrtf(var + GN_EPS);
    int b = blk / NG, g = blk % NG;
    int c = g * CPG + threadIdx.x;
    float sc = gn_w[c] * rstd;
    scale[b * NC + c] = sc;
    shift[b * NC + c] = gn_b[c] - mean * sc;
  }
}

// ---------------------------------------------------------------------------
// Kernel 2: normalize + transpose x[c][p] fp32 -> xnT[p][c] bf16 via LDS.
// ---------------------------------------------------------------------------
__global__ __launch_bounds__(256) void k_xnT(
    const float* __restrict__ x, const float* __restrict__ scale,
    const float* __restrict__ shift, __bf16* __restrict__ xnT) {
  __shared__ __bf16 t[64 * XSTR];
  int p0 = blockIdx.x * 64;
  int b = blockIdx.y;
  int w = threadIdx.x >> 6, lane = threadIdx.x & 63;
  const float* xb = x + (size_t)b * NC * NHW;
  const float* scb = scale + b * NC;
  const float* shb = shift + b * NC;
#pragma unroll 8
  for (int i = 0; i < 64; ++i) {
    int c = i * 4 + w;
    float v = xb[(size_t)c * NHW + p0 + lane] * scb[c] + shb[c];
    t[lane * XSTR + c] = (__bf16)v;
  }
  __syncthreads();
#pragma unroll
  for (int i = 0; i < 8; ++i) {
    int row = i * 8 + w * 2 + (lane >> 5);
    int c8 = (lane & 31) * 8;
    bf16x8 v8 = *(const bf16x8*)&t[row * XSTR + c8];
    *(bf16x8*)&xnT[((size_t)b * NHW + p0 + row) * NC + c8] = v8;
  }
}

// ---------------------------------------------------------------------------
// Kernel 3: QKV GEMM. Block: 128p x 64o, 4 waves m-split (32p each).
// grid: 18pg x 4oq x 8b = 576; b = blk&7 (XCD locality).
// ---------------------------------------------------------------------------
__global__ __launch_bounds__(256) void k_qkv(
    const __bf16* __restrict__ xnT,
    const __bf16* __restrict__ Wqb, const __bf16* __restrict__ Wkb,
    const __bf16* __restrict__ Wvb,
    const float* __restrict__ bq, const float* __restrict__ bk,
    const float* __restrict__ bv,
    __bf16* __restrict__ qT, __bf16* __restrict__ kT,
    __bf16* __restrict__ vbuf) {
  __shared__ __bf16 tile[9216];  // q/k: [128][72]; v: [64][136]
  int blk = blockIdx.x;
  int b = blk & 7;
  int r = blk >> 3;
  int oq = r & 3;
  int pg = r >> 2;
  int p0 = pg * 128, o0 = oq * 64;
  int tid = threadIdx.x;
  int w = tid >> 6, lane = tid & 63;
  int col = lane & 15, quad = lane >> 4;

  const __bf16* xrow =
      xnT + ((size_t)b * NHW + p0 + w * 32 + col) * NC + quad * 8;
  bf16x8 xf[2][8];
#pragma unroll
  for (int mt = 0; mt < 2; ++mt)
#pragma unroll
    for (int ks = 0; ks < 8; ++ks)
      xf[mt][ks] = *(const bf16x8*)(xrow + (size_t)mt * 16 * NC + ks * 32);

#pragma unroll
  for (int t = 0; t < 3; ++t) {
    const __bf16* W = t == 0 ? Wqb : (t == 1 ? Wkb : Wvb);
    const float* bias = t == 0 ? bq : (t == 1 ? bk : bv);
    f32x4 acc[2][4];
#pragma unroll
    for (int mt = 0; mt < 2; ++mt)
#pragma unroll
      for (int nt = 0; nt < 4; ++nt) acc[mt][nt] = (f32x4){0.f, 0.f, 0.f, 0.f};
#pragma unroll
    for (int nt = 0; nt < 4; ++nt) {
      const __bf16* wrow = W + ((size_t)(o0 + nt * 16 + col)) * NC + quad * 8;
#pragma unroll
      for (int ks = 0; ks < 8; ++ks) {
        bf16x8 wf = *(const bf16x8*)(wrow + ks * 32);
        acc[0][nt] = MFMA(xf[0][ks], wf, acc[0][nt]);
        acc[1][nt] = MFMA(xf[1][ks], wf, acc[1][nt]);
      }
    }
    if (t > 0) __syncthreads();
    if (t < 2) {
#pragma unroll
      for (int mt = 0; mt < 2; ++mt)
#pragma unroll
        for (int nt = 0; nt < 4; ++nt) {
          float bc = bias[o0 + nt * 16 + col];
#pragma unroll
          for (int reg = 0; reg < 4; ++reg) {
            int row = w * 32 + mt * 16 + quad * 4 + reg;
            tile[row * 72 + nt * 16 + col] = (__bf16)(acc[mt][nt][reg] + bc);
          }
        }
      __syncthreads();
      __bf16* dst = t == 0 ? qT : kT;
#pragma unroll
      for (int pass = 0; pass < 4; ++pass) {
        int unit = pass * 256 + tid;
        int row = unit >> 3, ch = unit & 7;
        bf16x8 v8 = *(const bf16x8*)&tile[row * 72 + ch * 8];
        *(bf16x8*)&dst[((size_t)b * NHW + p0 + row) * NC + o0 + ch * 8] = v8;
      }
    } else {
#pragma unroll
      for (int mt = 0; mt < 2; ++mt)
#pragma unroll
        for (int nt = 0; nt < 4; ++nt) {
          float bc = bias[o0 + nt * 16 + col];
#pragma unroll
          for (int reg = 0; reg < 4; ++reg) {
            int p = w * 32 + mt * 16 + quad * 4 + reg;
            tile[(nt * 16 + col) * 136 + p] = (__bf16)(acc[mt][nt][reg] + bc);
          }
        }
      __syncthreads();
#pragma unroll
      for (int pass = 0; pass < 4; ++pass) {
        int unit = pass * 256 + tid;
        int row = unit >> 4, ch = unit & 15;
        bf16x8 v8 = *(const bf16x8*)&tile[row * 136 + ch * 8];
        *(bf16x8*)&vbuf[((size_t)b * NC + o0 + row) * NHW + p0 + ch * 8] = v8;
      }
    }
  }
}

// ---------------------------------------------------------------------------
// Kernel 4: stage A — S = Q K^T (128q x 64k), P = exp(S/16) -> HBM in
// block-tiled layout [(b*18+qg)*36+kt][128][64] (contiguous 16 KB per block).
// Epilogue tile is f32 [128][68]: conflict-free writes, balanced b128 reads.
// grid 18qg x 36kt x 8b = 5184; b = blk&7.
// ---------------------------------------------------------------------------
__global__ __launch_bounds__(256, 4) void k_sexp(
    const __bf16* __restrict__ qT, const __bf16* __restrict__ kT,
    __bf16* __restrict__ P, float* __restrict__ lsum) {
  __shared__ __align__(16) char smem[128 * PTSTR * 4];  // 34816 B
  __bf16* sk = (__bf16*)smem;  // K tile [64][256] = 32768 B (aliased)
  float* pt = (float*)smem;    // epilogue tile [128][68] f32
  int blk = blockIdx.x;
  int b = blk & 7;
  int r = blk >> 3;
  int kt = r % 36;
  int qg = r / 36;
  int q0 = qg * 128, k0 = kt * 64;
  int tid = threadIdx.x;
  int w = tid >> 6, lane = tid & 63;
  int col = lane & 15, quad = lane >> 4;

  // ---- stage K tile (swizzled) ----
  {
    int sub = lane >> 5;
    int p5 = lane & 31;
#pragma unroll
    for (int j = 0; j < 8; ++j) {
      int r0 = w * 16 + j * 2;
      int rloc = r0 + sub;
      int g = p5 ^ (rloc & 7);
      const __bf16* gp = kT + ((size_t)b * NHW + k0 + rloc) * NC + g * 8;
      async_lds16(gp, (void*)&sk[r0 * 256]);
    }
  }
  // ---- Q fragments (direct) ----
  const __bf16* qrow =
      qT + ((size_t)b * NHW + q0 + w * 32 + col) * NC + quad * 8;
  bf16x8 qf[2][8];
#pragma unroll
  for (int mt = 0; mt < 2; ++mt)
#pragma unroll
    for (int ks = 0; ks < 8; ++ks)
      qf[mt][ks] = *(const bf16x8*)(qrow + (size_t)mt * 16 * NC + ks * 32);
  __syncthreads();

  f32x4 sacc[2][4];
#pragma unroll
  for (int mt = 0; mt < 2; ++mt)
#pragma unroll
    for (int nt = 0; nt < 4; ++nt) sacc[mt][nt] = (f32x4){0.f, 0.f, 0.f, 0.f};
  int c7 = col & 7;
#pragma unroll
  for (int nt = 0; nt < 4; ++nt) {
    int rrow = nt * 16 + col;
#pragma unroll
    for (int ks = 0; ks < 8; ++ks) {
      int c = ks * 4 + quad;
      bf16x8 kf = *(const bf16x8*)&sk[rrow * 256 + ((c ^ c7) << 3)];
      sacc[0][nt] = MFMA(qf[0][ks], kf, sacc[0][nt]);
      sacc[1][nt] = MFMA(qf[1][ks], kf, sacc[1][nt]);
    }
  }
  // ---- exp + row sums ----
#pragma unroll
  for (int mt = 0; mt < 2; ++mt)
#pragma unroll
    for (int reg = 0; reg < 4; ++reg) {
      float rs = 0.f;
#pragma unroll
      for (int nt = 0; nt < 4; ++nt) {
        float e = __expf(sacc[mt][nt][reg] * ATT_SCALE);
        sacc[mt][nt][reg] = e;
        rs += e;
      }
      rs += __shfl_xor(rs, 1);
      rs += __shfl_xor(rs, 2);
      rs += __shfl_xor(rs, 4);
      rs += __shfl_xor(rs, 8);
      if (col == 0) {
        int row = w * 32 + mt * 16 + quad * 4 + reg;
        atomicAdd(&lsum[(size_t)b * NHW + q0 + row], rs);
      }
    }
  __syncthreads();  // sk reads done before pt overwrite
#pragma unroll
  for (int mt = 0; mt < 2; ++mt)
#pragma unroll
    for (int nt = 0; nt < 4; ++nt)
#pragma unroll
      for (int reg = 0; reg < 4; ++reg) {
        int row = w * 32 + mt * 16 + quad * 4 + reg;
        pt[row * PTSTR + nt * 16 + col] = sacc[mt][nt][reg];
      }
  __syncthreads();
  // ---- pack + contiguous tiled store ----
  __bf16* dst = P + ((size_t)((b * 18 + qg) * 36 + kt)) * 8192;
#pragma unroll
  for (int pass = 0; pass < 4; ++pass) {
    int unit = pass * 256 + tid;
    int row = unit >> 3, ch = unit & 7;
    f32x4 a = *(const f32x4*)&pt[row * PTSTR + ch * 8];
    f32x4 bqv = *(const f32x4*)&pt[row * PTSTR + ch * 8 + 4];
    bf16x8 v8;
    v8[0] = (__bf16)a[0]; v8[1] = (__bf16)a[1];
    v8[2] = (__bf16)a[2]; v8[3] = (__bf16)a[3];
    v8[4] = (__bf16)bqv[0]; v8[5] = (__bf16)bqv[1];
    v8[6] = (__bf16)bqv[2]; v8[7] = (__bf16)bqv[3];
    *(bf16x8*)&dst[(size_t)unit * 8] = v8;
  }
}

// ---------------------------------------------------------------------------
// Kernel 5: stage B — out[c][q] = (V x P^T)[c][q] / lsum[q].
// Block: 32q x 256c (4 waves x 64c). NO LDS, NO barriers: V and P fragments
// read directly from global (P block-tiled -> 64B-coalesced; same P address
// across waves -> L1 broadcast; V is XCD-L2-resident).
// grid: 72qb x 8b = 576; b = blk&7.
// ---------------------------------------------------------------------------
__global__ __launch_bounds__(256, 4) void k_pv(
    const __bf16* __restrict__ P, const __bf16* __restrict__ vbuf,
    const float* __restrict__ lsum, float* __restrict__ out) {
  int blk = blockIdx.x;
  int b = blk & 7;
  int qb = blk >> 3;        // 0..71
  int q0 = qb * 32;
  int qg = qb >> 2, qsub = qb & 3;
  int tid = threadIdx.x;
  int w = tid >> 6, lane = tid & 63;
  int col = lane & 15, quad = lane >> 4;

  const __bf16* ptile =
      P + ((size_t)(b * 18 + qg) * 36) * 8192 + (size_t)qsub * 2048;
  const __bf16* vrow =
      vbuf + ((size_t)b * NC + w * 64 + col) * NHW + quad * 8;

  f32x4 acc[4][2];  // [ct][nt]
#pragma unroll
  for (int ct = 0; ct < 4; ++ct)
#pragma unroll
    for (int nt = 0; nt < 2; ++nt) acc[ct][nt] = (f32x4){0.f, 0.f, 0.f, 0.f};

  for (int kt = 0; kt < 36; ++kt) {
    const __bf16* pk = ptile + (size_t)kt * 8192;
    bf16x8 pf[2][2];
#pragma unroll
    for (int nt = 0; nt < 2; ++nt)
#pragma unroll
      for (int ks = 0; ks < 2; ++ks)
        pf[nt][ks] =
            *(const bf16x8*)(pk + (nt * 16 + col) * 64 + ks * 32 + quad * 8);
    const __bf16* vk = vrow + kt * 64;
#pragma unroll
    for (int ct = 0; ct < 4; ++ct) {
#pragma unroll
      for (int ks = 0; ks < 2; ++ks) {
        bf16x8 vf = *(const bf16x8*)(vk + (size_t)ct * 16 * NHW + ks * 32);
#pragma unroll
        for (int nt = 0; nt < 2; ++nt)
          acc[ct][nt] = MFMA(vf, pf[nt][ks], acc[ct][nt]);
      }
    }
  }
  float inv[2];
#pragma unroll
  for (int nt = 0; nt < 2; ++nt)
    inv[nt] = 1.f / lsum[(size_t)b * NHW + q0 + nt * 16 + col];
  float* ob = out + (size_t)b * NC * NHW + q0;
#pragma unroll
  for (int ct = 0; ct < 4; ++ct)
#pragma unroll
    for (int reg = 0; reg < 4; ++reg) {
      int c = w * 64 + ct * 16 + quad * 4 + reg;
#pragma unroll
      for (int nt = 0; nt < 2; ++nt)
        ob[(size_t)c * NHW + nt * 16 + col] = acc[ct][nt][reg] * inv[nt];
    }
}

// ---------------------------------------------------------------------------
extern "C" void kernel_launch(void* const* d_in, const int* in_sizes, int n_in,
                              void* d_out, int out_size, void* d_ws,
                              size_t ws_size, hipStream_t stream) {
  const float* x   = (const float*)d_in[0];
  const float* Wq  = (const float*)d_in[1];
  const float* bq  = (const float*)d_in[2];
  const float* Wk  = (const float*)d_in[3];
  const float* bk  = (const float*)d_in[4];
  const float* Wv  = (const float*)d_in[5];
  const float* bv  = (const float*)d_in[6];
  const float* gnw = (const float*)d_in[7];
  const float* gnb = (const float*)d_in[8];
  float* out = (float*)d_out;

  const size_t per = (size_t)NB * NC * NHW;          // 4,718,592 elems
  const size_t psz = (size_t)NB * NHW * NHW * 2;     // 84,934,656 B
  char* wsb = (char*)d_ws;
  __bf16* qT   = (__bf16*)wsb;
  __bf16* kT   = (__bf16*)(wsb + per * 2);
  __bf16* vbuf = (__bf16*)(wsb + per * 4);
  __bf16* xnT  = (__bf16*)(wsb + per * 6);  // dead after k_qkv
  __bf16* P    = (__bf16*)(wsb + per * 6);  // aliases xnT region, 85 MB
  char* tail   = wsb + per * 6 + psz;
  __bf16* Wqb  = (__bf16*)tail;
  __bf16* Wkb  = Wqb + NC * NC;
  __bf16* Wvb  = Wkb + NC * NC;
  float* scale = (float*)(Wvb + NC * NC);
  float* shift = scale + NB * NC;
  float* lsum  = shift + NB * NC;           // NB*NHW floats

  hipMemsetAsync(lsum, 0, (size_t)NB * NHW * sizeof(float), stream);
  hipLaunchKernelGGL(k_prep, dim3(448), dim3(256), 0, stream,
                     x, gnw, gnb, scale, shift, Wq, Wk, Wv, Wqb, Wkb, Wvb);
  hipLaunchKernelGGL(k_xnT, dim3(NHW / 64, NB), dim3(256), 0, stream,
                     x, scale, shift, xnT);
  hipLaunchKernelGGL(k_qkv, dim3(576), dim3(256), 0, stream,
                     xnT, Wqb, Wkb, Wvb, bq, bk, bv, qT, kT, vbuf);
  hipLaunchKernelGGL(k_sexp, dim3(5184), dim3(256), 0, stream,
                     qT, kT, P, lsum);
  hipLaunchKernelGGL(k_pv, dim3(576), dim3(256), 0, stream,
                     P, vbuf, lsum, out);
}